// Round 13
// baseline (87.343 us; speedup 1.0000x reference)
//
#include <hip/hip_runtime.h>
#include <math.h>

// Problem constants
#define Mm 4096   // batch B
#define Nn 4096   // 4*H, column map: c = (h>>4)*64 + g*16 + (h&15)
#define Kk 2048   // D + H

typedef __bf16 bf16x8 __attribute__((ext_vector_type(8)));
typedef float f32x4 __attribute__((ext_vector_type(4)));

__device__ __forceinline__ unsigned short f2bf(float f) {
    union { float f; unsigned u; } v; v.f = f;
    unsigned r = v.u + 0x7FFFu + ((v.u >> 16) & 1u);  // RNE
    return (unsigned short)(r >> 16);
}

__device__ __forceinline__ float fast_tanh(float x) {
    return 1.f - 2.f / (1.f + __expf(2.f * x));
}

// ---------------------------------------------------------------------------
// Kernel 1: pack x|h -> Xcat bf16 [4096][2048]
//   W|U -> Wcat bf16 [4096][2048], row n' = (h>>4)*64 + g*16 + (h&15)
//   bsum[4h+g] = bW+bU.
// ---------------------------------------------------------------------------
__global__ void pack_bf16(const float* __restrict__ x, const float* __restrict__ h,
                          const float* __restrict__ W, const float* __restrict__ U,
                          const float* __restrict__ bW, const float* __restrict__ bU,
                          unsigned short* __restrict__ Xc, unsigned short* __restrict__ Wc,
                          float* __restrict__ bsum) {
    if (blockIdx.x == 0) {
#pragma unroll
        for (int j = 0; j < 16; ++j) {
            int n = threadIdx.x * 16 + j;
            int hh = n >> 2, g = n & 3;
            bsum[n] = bW[g * 1024 + hh] + bU[g * 1024 + hh];
        }
    }
    const int PER = (4096 * 1024) / 4;
    for (int t = blockIdx.x * blockDim.x + threadIdx.x; t < 4 * PER;
         t += gridDim.x * blockDim.x) {
        int region = t >> 20;
        int i = t & (PER - 1);
        int row = i >> 8;
        int c4  = i & 255;
        const float* src = (region == 0) ? x : (region == 1) ? h : (region == 2) ? W : U;
        float4 v = reinterpret_cast<const float4*>(src)[i];
        ushort4 o;
        o.x = f2bf(v.x); o.y = f2bf(v.y); o.z = f2bf(v.z); o.w = f2bf(v.w);
        if (region < 2) {
            *reinterpret_cast<ushort4*>(Xc + (size_t)row * 2048 + (region << 10) + c4 * 4) = o;
        } else {
            int g = row >> 10, hh = row & 1023;
            int np = ((hh >> 4) << 6) + (g << 4) + (hh & 15);
            *reinterpret_cast<ushort4*>(Wc + (size_t)np * 2048 + ((region & 1) << 10) + c4 * 4) = o;
        }
    }
}

// ---------------------------------------------------------------------------
// Kernel 2: 256x256 GEMM, 2-barrier-per-K-tile interval schedule,
//           register-only fused LSTM epilogue.
// ---------------------------------------------------------------------------
__device__ __forceinline__ void gl16(const void* g, void* l) {
    __builtin_amdgcn_global_load_lds(
        (const __attribute__((address_space(1))) void*)g,
        (__attribute__((address_space(3))) void*)l, 16, 0, 0);
}

#define A_OFF(p, ah) (((p) * 2 + (ah)) * 16384)
#define B_OFF(p, hb) (65536 + ((p) * 2 + (hb)) * 16384)

__global__ __launch_bounds__(512, 2) void gemm_8ph(const unsigned short* __restrict__ A,
                                                   const unsigned short* __restrict__ Bw,
                                                   const float* __restrict__ bsum,
                                                   const float* __restrict__ cprev,
                                                   float* __restrict__ out) {
    extern __shared__ char lds[];
    const int tid = threadIdx.x, lane = tid & 63, wave = tid >> 6;
    const int wm = wave >> 2, wn = wave & 3;

    const int bid = blockIdx.x;
    const int swz = (bid & 7) * 32 + (bid >> 3);
    const int bm = swz & 15, bn = swz >> 4;
    const size_t Crow0 = (size_t)bm * 256, Ccol0 = (size_t)bn * 256;

    // ---- staging source base addresses (inverse-swizzled global)
    const int srow = wave * 8 + (lane >> 3);
    const int scolswz = (((lane & 7) ^ (lane >> 3)) << 4);
    const char* aBase = (const char*)A  + (size_t)(Crow0 + srow) * 4096 + scolswz;
    const char* bBase = (const char*)Bw + (size_t)(Ccol0 + srow) * 4096 + scolswz;

    // j-block byte offsets in global: row + {ah*128 + j*64} -> *4096 bytes
#define STG_A(p, ah, kb) do { \
        gl16(aBase + (size_t)(ah) * 524288 + (kb),          lds + A_OFF(p, ah) + wave * 1024); \
        gl16(aBase + (size_t)(ah) * 524288 + 262144 + (kb), lds + A_OFF(p, ah) + 8192 + wave * 1024); } while (0)
#define STG_B(p, hb, kb) do { \
        gl16(bBase + (size_t)(hb) * 524288 + (kb),          lds + B_OFF(p, hb) + wave * 1024); \
        gl16(bBase + (size_t)(hb) * 524288 + 262144 + (kb), lds + B_OFF(p, hb) + 8192 + wave * 1024); } while (0)

    // ---- LDS read addressing (swizzled), 16x16x32 frags
    const int arowB = (wm * 64 + (lane & 15)) * 128;
    const int browB = ((wn & 1) * 64 + (lane & 15)) * 128;
    const int c0 = (((lane >> 4) << 4)) ^ ((lane & 7) << 4);
    const int c1 = (64 + ((lane >> 4) << 4)) ^ ((lane & 7) << 4);
    const int bhb = wn >> 1;

#define LDA(p, ah, mfl, ck) (*(const bf16x8*)(lds + A_OFF(p, ah) + arowB + (mfl) * 2048 + (ck)))
#define LDB(p, nf, ck)      (*(const bf16x8*)(lds + B_OFF(p, bhb) + browB + (nf) * 2048 + (ck)))

    f32x4 acc[2][4][4] = {};
    bf16x8 bb0, bb1, bb2, bb3, bb4, bb5, bb6, bb7;   // B(t), single-buffered
    bf16x8 aa0, aa1, aa2, aa3, aa4, aa5, aa6, aa7;   // A0 quads
    bf16x8 ab0, ab1, ab2, ab3, ab4, ab5, ab6, ab7;   // A1 quads

#define MFMA(a, b, c) __builtin_amdgcn_mfma_f32_16x16x32_bf16(a, b, c, 0, 0, 0)
    // 32 MFMAs: all 16 accs at k0 (even frags), then all 16 at k1 (odd).
    // Per-acc accumulation order k0-then-k1 (bitwise-identical to before).
#define CL32(ah, A0_, A1_, A2_, A3_, A4_, A5_, A6_, A7_) \
    acc[ah][0][0] = MFMA(A0_, bb0, acc[ah][0][0]); \
    acc[ah][0][1] = MFMA(A0_, bb2, acc[ah][0][1]); \
    acc[ah][0][2] = MFMA(A0_, bb4, acc[ah][0][2]); \
    acc[ah][0][3] = MFMA(A0_, bb6, acc[ah][0][3]); \
    acc[ah][1][0] = MFMA(A2_, bb0, acc[ah][1][0]); \
    acc[ah][1][1] = MFMA(A2_, bb2, acc[ah][1][1]); \
    acc[ah][1][2] = MFMA(A2_, bb4, acc[ah][1][2]); \
    acc[ah][1][3] = MFMA(A2_, bb6, acc[ah][1][3]); \
    acc[ah][2][0] = MFMA(A4_, bb0, acc[ah][2][0]); \
    acc[ah][2][1] = MFMA(A4_, bb2, acc[ah][2][1]); \
    acc[ah][2][2] = MFMA(A4_, bb4, acc[ah][2][2]); \
    acc[ah][2][3] = MFMA(A4_, bb6, acc[ah][2][3]); \
    acc[ah][3][0] = MFMA(A6_, bb0, acc[ah][3][0]); \
    acc[ah][3][1] = MFMA(A6_, bb2, acc[ah][3][1]); \
    acc[ah][3][2] = MFMA(A6_, bb4, acc[ah][3][2]); \
    acc[ah][3][3] = MFMA(A6_, bb6, acc[ah][3][3]); \
    acc[ah][0][0] = MFMA(A1_, bb1, acc[ah][0][0]); \
    acc[ah][0][1] = MFMA(A1_, bb3, acc[ah][0][1]); \
    acc[ah][0][2] = MFMA(A1_, bb5, acc[ah][0][2]); \
    acc[ah][0][3] = MFMA(A1_, bb7, acc[ah][0][3]); \
    acc[ah][1][0] = MFMA(A3_, bb1, acc[ah][1][0]); \
    acc[ah][1][1] = MFMA(A3_, bb3, acc[ah][1][1]); \
    acc[ah][1][2] = MFMA(A3_, bb5, acc[ah][1][2]); \
    acc[ah][1][3] = MFMA(A3_, bb7, acc[ah][1][3]); \
    acc[ah][2][0] = MFMA(A5_, bb1, acc[ah][2][0]); \
    acc[ah][2][1] = MFMA(A5_, bb3, acc[ah][2][1]); \
    acc[ah][2][2] = MFMA(A5_, bb5, acc[ah][2][2]); \
    acc[ah][2][3] = MFMA(A5_, bb7, acc[ah][2][3]); \
    acc[ah][3][0] = MFMA(A7_, bb1, acc[ah][3][0]); \
    acc[ah][3][1] = MFMA(A7_, bb3, acc[ah][3][1]); \
    acc[ah][3][2] = MFMA(A7_, bb5, acc[ah][3][2]); \
    acc[ah][3][3] = MFMA(A7_, bb7, acc[ah][3][3]);

#define SGB0 __builtin_amdgcn_sched_barrier(0)
#define SBAR __builtin_amdgcn_s_barrier()

    // 2 barriers per K-tile. Drain ledger (verified):
    //  int-A(t): reads B(t)[staged t-2]+A1(t)[staged int-A(t-1), drained
    //    int-B(t-1) vmcnt(6)]; cluster A0(t)xB(t); STG A1(t+1) [slot last
    //    read int-A(t-1)]; vmcnt(2) drains {A0,B0,B1}(t+1); SBAR.
    //  int-B(t): reads A0(t+1)[drained above]; cluster A1(t)xB(t); STG
    //    A0(t+2),B0(t+2),B1(t+2) [slots last read int-B(t-1)/int-A(t)];
    //    vmcnt(6) drains A1(t+1); SBAR.
#define GROUP(p, kbA1, kbT2) \
    { \
        /* int-A */ \
        bb0 = LDB(p, 0, c0); bb1 = LDB(p, 0, c1); bb2 = LDB(p, 1, c0); bb3 = LDB(p, 1, c1); \
        bb4 = LDB(p, 2, c0); bb5 = LDB(p, 2, c1); bb6 = LDB(p, 3, c0); bb7 = LDB(p, 3, c1); \
        ab0 = LDA(p, 1, 0, c0); ab1 = LDA(p, 1, 0, c1); ab2 = LDA(p, 1, 1, c0); ab3 = LDA(p, 1, 1, c1); \
        ab4 = LDA(p, 1, 2, c0); ab5 = LDA(p, 1, 2, c1); ab6 = LDA(p, 1, 3, c0); ab7 = LDA(p, 1, 3, c1); \
        SGB0; \
        __builtin_amdgcn_s_setprio(1); \
        CL32(0, aa0, aa1, aa2, aa3, aa4, aa5, aa6, aa7) \
        __builtin_amdgcn_s_setprio(0); \
        STG_A((p) ^ 1, 1, kbA1); \
        asm volatile("s_waitcnt vmcnt(2)" ::: "memory"); \
        SBAR; \
        /* int-B */ \
        aa0 = LDA((p) ^ 1, 0, 0, c0); aa1 = LDA((p) ^ 1, 0, 0, c1); \
        aa2 = LDA((p) ^ 1, 0, 1, c0); aa3 = LDA((p) ^ 1, 0, 1, c1); \
        aa4 = LDA((p) ^ 1, 0, 2, c0); aa5 = LDA((p) ^ 1, 0, 2, c1); \
        aa6 = LDA((p) ^ 1, 0, 3, c0); aa7 = LDA((p) ^ 1, 0, 3, c1); \
        SGB0; \
        __builtin_amdgcn_s_setprio(1); \
        CL32(1, ab0, ab1, ab2, ab3, ab4, ab5, ab6, ab7) \
        __builtin_amdgcn_s_setprio(0); \
        STG_A(p, 0, kbT2); \
        STG_B(p, 0, kbT2); \
        STG_B(p, 1, kbT2); \
        asm volatile("s_waitcnt vmcnt(6)" ::: "memory"); \
        SBAR; \
    }

    // ---- prologue
    STG_A(0, 0, 0);                       // A0(0)
    STG_B(0, 0, 0); STG_B(0, 1, 0);       // B(0)
    STG_A(0, 1, 0);                       // A1(0)
    asm volatile("s_waitcnt vmcnt(0)" ::: "memory");
    __builtin_amdgcn_s_barrier();
    // A0(0) -> regs (data drained above)
    aa0 = LDA(0, 0, 0, c0); aa1 = LDA(0, 0, 0, c1);
    aa2 = LDA(0, 0, 1, c0); aa3 = LDA(0, 0, 1, c1);
    aa4 = LDA(0, 0, 2, c0); aa5 = LDA(0, 0, 2, c1);
    aa6 = LDA(0, 0, 3, c0); aa7 = LDA(0, 0, 3, c1);
    // steady-state in-flight set {A0(1),B0(1),B1(1)}
    STG_A(1, 0, 128);
    STG_B(1, 0, 128); STG_B(1, 1, 128);

    // ---- main loop: 16 iterations x 2 K-tiles (K = 2048 = 32 x 64)
    for (int it = 0; it < 16; ++it) {
        const int t0 = 2 * it;
        const size_t kA1_0 = (size_t)(t0 + 1) * 128;
        const size_t kT2_0 = (t0 + 2 <= 31) ? (size_t)(t0 + 2) * 128 : 0;
        const size_t kA1_1 = kT2_0;
        const size_t kT2_1 = (t0 + 3 <= 31) ? (size_t)(t0 + 3) * 128 : 0;
        GROUP(0, kA1_0, kT2_0)
        GROUP(1, kA1_1, kT2_1)
    }

    // ---- register-only fused LSTM epilogue ---------------------------------
    const int hl = lane & 15;
    const int er0 = (lane >> 4) * 4;
    const int myh = (int)(Ccol0 >> 2) + wn * 16 + hl;
    const f32x4 bs = *(const f32x4*)(bsum + (size_t)myh * 4);

    float cp[2][4][4];
#pragma unroll
    for (int ah = 0; ah < 2; ++ah)
#pragma unroll
        for (int mf = 0; mf < 4; ++mf)
#pragma unroll
            for (int r = 0; r < 4; ++r)
                cp[ah][mf][r] = cprev[(size_t)(Crow0 + ah * 128 + wm * 64 + mf * 16 + er0 + r) * 1024 + myh];

#pragma unroll
    for (int ah = 0; ah < 2; ++ah)
#pragma unroll
        for (int mf = 0; mf < 4; ++mf)
#pragma unroll
            for (int r = 0; r < 4; ++r) {
                float gi = acc[ah][mf][0][r] + bs[0];
                float gf = acc[ah][mf][1][r] + bs[1];
                float go = acc[ah][mf][2][r] + bs[2];
                float gz = acc[ah][mf][3][r] + bs[3];
                float iv = 1.f / (1.f + __expf(-gi));
                float fv = 1.f / (1.f + __expf(-gf));
                float ov = 1.f / (1.f + __expf(-go));
                float zv = fast_tanh(gz);
                float cc = fmaf(iv, zv, fv * cp[ah][mf][r]);
                float hv = ov * fast_tanh(cc);
                const size_t oidx =
                    (size_t)(Crow0 + ah * 128 + wm * 64 + mf * 16 + er0 + r) * 1024 + myh;
                out[oidx] = hv;
                out[(1 << 22) + oidx] = cc;
            }

    // drain phantom prefetches before LDS dealloc at endpgm
    asm volatile("s_waitcnt vmcnt(0)" ::: "memory");
}

// ---------------------------------------------------------------------------
extern "C" void kernel_launch(void* const* d_in, const int* in_sizes, int n_in,
                              void* d_out, int out_size, void* d_ws, size_t ws_size,
                              hipStream_t stream) {
    const float* x  = (const float*)d_in[0];
    const float* h  = (const float*)d_in[1];
    const float* c  = (const float*)d_in[2];
    const float* W  = (const float*)d_in[3];
    const float* bW = (const float*)d_in[4];
    const float* U  = (const float*)d_in[5];
    const float* bU = (const float*)d_in[6];
    float* out = (float*)d_out;

    char* ws = (char*)d_ws;
    unsigned short* Xc = (unsigned short*)ws;                         // 16 MB
    unsigned short* Wc = (unsigned short*)(ws + ((size_t)16 << 20));  // 16 MB
    float* bsum = (float*)(ws + ((size_t)32 << 20));                  // 16 KB

    (void)hipFuncSetAttribute((const void*)gemm_8ph,
                              hipFuncAttributeMaxDynamicSharedMemorySize, 131072);

    hipLaunchKernelGGL(pack_bf16, dim3(2048), dim3(256), 0, stream,
                       x, h, W, U, bW, bU, Xc, Wc, bsum);
    hipLaunchKernelGGL(gemm_8ph, dim3(256), dim3(512), 131072, stream,
                       Xc, Wc, bsum, c, out);
}

// Round 14
// 83.879 us; speedup vs baseline: 1.0413x; 1.0413x over previous
//
#include <hip/hip_runtime.h>
#include <math.h>

// Problem constants
#define Mm 4096   // batch B
#define Nn 4096   // 4*H, column map: c = (h>>4)*64 + g*16 + (h&15)
#define Kk 2048   // D + H

typedef __bf16 bf16x8 __attribute__((ext_vector_type(8)));
typedef float f32x4 __attribute__((ext_vector_type(4)));

__device__ __forceinline__ unsigned short f2bf(float f) {
    union { float f; unsigned u; } v; v.f = f;
    unsigned r = v.u + 0x7FFFu + ((v.u >> 16) & 1u);  // RNE
    return (unsigned short)(r >> 16);
}

__device__ __forceinline__ float fast_tanh(float x) {
    return 1.f - 2.f / (1.f + __expf(2.f * x));
}

// ---------------------------------------------------------------------------
// Kernel 1: pack x|h -> Xcat bf16 [4096][2048]
//   W|U -> Wcat bf16 [4096][2048], row n' = (h>>4)*64 + g*16 + (h&15)
//   bsum[4h+g] = bW+bU.
// ---------------------------------------------------------------------------
__global__ void pack_bf16(const float* __restrict__ x, const float* __restrict__ h,
                          const float* __restrict__ W, const float* __restrict__ U,
                          const float* __restrict__ bW, const float* __restrict__ bU,
                          unsigned short* __restrict__ Xc, unsigned short* __restrict__ Wc,
                          float* __restrict__ bsum) {
    if (blockIdx.x == 0) {
#pragma unroll
        for (int j = 0; j < 16; ++j) {
            int n = threadIdx.x * 16 + j;
            int hh = n >> 2, g = n & 3;
            bsum[n] = bW[g * 1024 + hh] + bU[g * 1024 + hh];
        }
    }
    const int PER = (4096 * 1024) / 4;
    for (int t = blockIdx.x * blockDim.x + threadIdx.x; t < 4 * PER;
         t += gridDim.x * blockDim.x) {
        int region = t >> 20;
        int i = t & (PER - 1);
        int row = i >> 8;
        int c4  = i & 255;
        const float* src = (region == 0) ? x : (region == 1) ? h : (region == 2) ? W : U;
        float4 v = reinterpret_cast<const float4*>(src)[i];
        ushort4 o;
        o.x = f2bf(v.x); o.y = f2bf(v.y); o.z = f2bf(v.z); o.w = f2bf(v.w);
        if (region < 2) {
            *reinterpret_cast<ushort4*>(Xc + (size_t)row * 2048 + (region << 10) + c4 * 4) = o;
        } else {
            int g = row >> 10, hh = row & 1023;
            int np = ((hh >> 4) << 6) + (g << 4) + (hh & 15);
            *reinterpret_cast<ushort4*>(Wc + (size_t)np * 2048 + ((region & 1) << 10) + c4 * 4) = o;
        }
    }
}

// ---------------------------------------------------------------------------
// Kernel 2: 256x256 GEMM, cross-phase pipelined A-quads (R10 schedule),
//           STG issued after the MFMA cluster, register-only LSTM epilogue.
// ---------------------------------------------------------------------------
__device__ __forceinline__ void gl16(const void* g, void* l) {
    __builtin_amdgcn_global_load_lds(
        (const __attribute__((address_space(1))) void*)g,
        (__attribute__((address_space(3))) void*)l, 16, 0, 0);
}

#define A_OFF(p, ah) (((p) * 2 + (ah)) * 16384)
#define B_OFF(p, hb) (65536 + ((p) * 2 + (hb)) * 16384)

__global__ __launch_bounds__(512, 2) void gemm_8ph(const unsigned short* __restrict__ A,
                                                   const unsigned short* __restrict__ Bw,
                                                   const float* __restrict__ bsum,
                                                   const float* __restrict__ cprev,
                                                   float* __restrict__ out) {
    extern __shared__ char lds[];
    const int tid = threadIdx.x, lane = tid & 63, wave = tid >> 6;
    const int wm = wave >> 2, wn = wave & 3;

    const int bid = blockIdx.x;
    const int swz = (bid & 7) * 32 + (bid >> 3);
    const int bm = swz & 15, bn = swz >> 4;
    const size_t Crow0 = (size_t)bm * 256, Ccol0 = (size_t)bn * 256;

    // ---- staging source addresses (inverse-swizzled global, linear LDS dest)
    const int srow = wave * 8 + (lane >> 3);
    const int scolswz = (((lane & 7) ^ (lane >> 3)) << 4);
    const char* aS[2][2];
    const char* bS[2][2];
#pragma unroll
    for (int ah = 0; ah < 2; ++ah)
#pragma unroll
        for (int j = 0; j < 2; ++j) {
            aS[ah][j] = (const char*)A  + (size_t)(Crow0 + ah * 128 + j * 64 + srow) * 4096 + scolswz;
            bS[ah][j] = (const char*)Bw + (size_t)(Ccol0 + ah * 128 + j * 64 + srow) * 4096 + scolswz;
        }

#define STG_A(p, ah, kb) do { \
        gl16(aS[ah][0] + (kb), lds + A_OFF(p, ah) + wave * 1024); \
        gl16(aS[ah][1] + (kb), lds + A_OFF(p, ah) + 8192 + wave * 1024); } while (0)
#define STG_B(p, hb, kb) do { \
        gl16(bS[hb][0] + (kb), lds + B_OFF(p, hb) + wave * 1024); \
        gl16(bS[hb][1] + (kb), lds + B_OFF(p, hb) + 8192 + wave * 1024); } while (0)

    // ---- LDS read addressing (swizzled), 16x16x32 frags
    const int arowB = (wm * 64 + (lane & 15)) * 128;
    const int browB = ((wn & 1) * 64 + (lane & 15)) * 128;
    const int c0 = (((lane >> 4) << 4)) ^ ((lane & 7) << 4);
    const int c1 = (64 + ((lane >> 4) << 4)) ^ ((lane & 7) << 4);
    const int bhb = wn >> 1;

#define LDA(p, ah, mfl, ck) (*(const bf16x8*)(lds + A_OFF(p, ah) + arowB + (mfl) * 2048 + (ck)))
#define LDB(p, nf, ck)      (*(const bf16x8*)(lds + B_OFF(p, bhb) + browB + (nf) * 2048 + (ck)))

    f32x4 acc[2][4][4] = {};

#define MFMA(a, b, c) __builtin_amdgcn_mfma_f32_16x16x32_bf16(a, b, c, 0, 0, 0)
    // 16 MFMAs per cluster, acc reuse distance 8; per-acc order k0 then k1.
#define MF16(ah, mfA, mfB, p00, p01, p10, p11) \
    acc[ah][mfA][0] = MFMA(p00, b00, acc[ah][mfA][0]); \
    acc[ah][mfA][1] = MFMA(p00, b10, acc[ah][mfA][1]); \
    acc[ah][mfA][2] = MFMA(p00, b20, acc[ah][mfA][2]); \
    acc[ah][mfA][3] = MFMA(p00, b30, acc[ah][mfA][3]); \
    acc[ah][mfB][0] = MFMA(p10, b00, acc[ah][mfB][0]); \
    acc[ah][mfB][1] = MFMA(p10, b10, acc[ah][mfB][1]); \
    acc[ah][mfB][2] = MFMA(p10, b20, acc[ah][mfB][2]); \
    acc[ah][mfB][3] = MFMA(p10, b30, acc[ah][mfB][3]); \
    acc[ah][mfA][0] = MFMA(p01, b01, acc[ah][mfA][0]); \
    acc[ah][mfA][1] = MFMA(p01, b11, acc[ah][mfA][1]); \
    acc[ah][mfA][2] = MFMA(p01, b21, acc[ah][mfA][2]); \
    acc[ah][mfA][3] = MFMA(p01, b31, acc[ah][mfA][3]); \
    acc[ah][mfB][0] = MFMA(p11, b01, acc[ah][mfB][0]); \
    acc[ah][mfB][1] = MFMA(p11, b11, acc[ah][mfB][1]); \
    acc[ah][mfB][2] = MFMA(p11, b21, acc[ah][mfB][2]); \
    acc[ah][mfB][3] = MFMA(p11, b31, acc[ah][mfB][3]);

#define SGB0 __builtin_amdgcn_sched_barrier(0)
#define SBAR __builtin_amdgcn_s_barrier()

    // R10 schedule with STG moved after the cluster. Per phase: one STG, one
    // vmcnt(6) (phases 1-3) -> wait sees 6+2=8 outstanding, drains the same
    // two oldest loads as before; barrier still follows STG so cross-wave
    // visibility points are unchanged. Stage slots: A1@ph1, B0@ph2, A0@ph3,
    // B1@ph4 (identical to the R2-verified ledger).
#define GROUP(p, kbA1, kbT2) \
    { \
        /* phi1: consume B+A0a (serial head), prefetch A0b */ \
        bf16x8 b00 = LDB(p, 0, c0), b01 = LDB(p, 0, c1), b10 = LDB(p, 1, c0), b11 = LDB(p, 1, c1); \
        bf16x8 b20 = LDB(p, 2, c0), b21 = LDB(p, 2, c1), b30 = LDB(p, 3, c0), b31 = LDB(p, 3, c1); \
        bf16x8 a0 = LDA(p, 0, 0, c0), a1 = LDA(p, 0, 0, c1); \
        bf16x8 a2 = LDA(p, 0, 1, c0), a3 = LDA(p, 0, 1, c1); \
        bf16x8 n0 = LDA(p, 0, 2, c0), n1 = LDA(p, 0, 2, c1); \
        bf16x8 n2 = LDA(p, 0, 3, c0), n3 = LDA(p, 0, 3, c1); \
        asm volatile("s_waitcnt vmcnt(6)" ::: "memory"); \
        SGB0; \
        __builtin_amdgcn_s_setprio(1); \
        MF16(0, 0, 1, a0, a1, a2, a3) \
        __builtin_amdgcn_s_setprio(0); \
        STG_A((p) ^ 1, 1, kbA1); \
        SBAR; \
        /* phi2: prefetch A1a, compute A0b */ \
        a0 = LDA(p, 1, 0, c0); a1 = LDA(p, 1, 0, c1); \
        a2 = LDA(p, 1, 1, c0); a3 = LDA(p, 1, 1, c1); \
        asm volatile("s_waitcnt vmcnt(6)" ::: "memory"); \
        SGB0; \
        __builtin_amdgcn_s_setprio(1); \
        MF16(0, 2, 3, n0, n1, n2, n3) \
        __builtin_amdgcn_s_setprio(0); \
        STG_B(p, 0, kbT2); \
        SBAR; \
        /* phi3: prefetch A1b, compute A1a */ \
        n0 = LDA(p, 1, 2, c0); n1 = LDA(p, 1, 2, c1); \
        n2 = LDA(p, 1, 3, c0); n3 = LDA(p, 1, 3, c1); \
        asm volatile("s_waitcnt vmcnt(6)" ::: "memory"); \
        SGB0; \
        __builtin_amdgcn_s_setprio(1); \
        MF16(1, 0, 1, a0, a1, a2, a3) \
        __builtin_amdgcn_s_setprio(0); \
        STG_A(p, 0, kbT2); \
        SBAR; \
        /* phi4: pure MFMA on A1b */ \
        SGB0; \
        __builtin_amdgcn_s_setprio(1); \
        MF16(1, 2, 3, n0, n1, n2, n3) \
        __builtin_amdgcn_s_setprio(0); \
        STG_B(p, 1, kbT2); \
        SBAR; \
    }

    // ---- prologue: 7 half-tiles in steady-state virtual order
    STG_B(0, 0, 0);
    STG_A(0, 0, 0);
    STG_B(0, 1, 0);
    STG_A(0, 1, 0);
    STG_B(1, 0, 128);
    STG_A(1, 0, 128);
    STG_B(1, 1, 128);
    asm volatile("s_waitcnt vmcnt(6)" ::: "memory");
    __builtin_amdgcn_s_barrier();

    // ---- main loop: 16 iterations x 2 K-tiles (K = 2048 = 32 x 64)
    for (int it = 0; it < 16; ++it) {
        const int t0 = 2 * it;
        const size_t kA1_0 = (size_t)(t0 + 1) * 128;
        const size_t kT2_0 = (t0 + 2 <= 31) ? (size_t)(t0 + 2) * 128 : 0;
        const size_t kA1_1 = kT2_0;
        const size_t kT2_1 = (t0 + 3 <= 31) ? (size_t)(t0 + 3) * 128 : 0;
        GROUP(0, kA1_0, kT2_0)
        GROUP(1, kA1_1, kT2_1)
    }

    // ---- register-only fused LSTM epilogue ---------------------------------
    const int hl = lane & 15;
    const int er0 = (lane >> 4) * 4;
    const int myh = (int)(Ccol0 >> 2) + wn * 16 + hl;
    const f32x4 bs = *(const f32x4*)(bsum + (size_t)myh * 4);

    float cp[2][4][4];
#pragma unroll
    for (int ah = 0; ah < 2; ++ah)
#pragma unroll
        for (int mf = 0; mf < 4; ++mf)
#pragma unroll
            for (int r = 0; r < 4; ++r)
                cp[ah][mf][r] = cprev[(size_t)(Crow0 + ah * 128 + wm * 64 + mf * 16 + er0 + r) * 1024 + myh];

#pragma unroll
    for (int ah = 0; ah < 2; ++ah)
#pragma unroll
        for (int mf = 0; mf < 4; ++mf)
#pragma unroll
            for (int r = 0; r < 4; ++r) {
                float gi = acc[ah][mf][0][r] + bs[0];
                float gf = acc[ah][mf][1][r] + bs[1];
                float go = acc[ah][mf][2][r] + bs[2];
                float gz = acc[ah][mf][3][r] + bs[3];
                float iv = 1.f / (1.f + __expf(-gi));
                float fv = 1.f / (1.f + __expf(-gf));
                float ov = 1.f / (1.f + __expf(-go));
                float zv = fast_tanh(gz);
                float cc = fmaf(iv, zv, fv * cp[ah][mf][r]);
                float hv = ov * fast_tanh(cc);
                const size_t oidx =
                    (size_t)(Crow0 + ah * 128 + wm * 64 + mf * 16 + er0 + r) * 1024 + myh;
                out[oidx] = hv;
                out[(1 << 22) + oidx] = cc;
            }

    // drain phantom prefetches before LDS dealloc at endpgm
    asm volatile("s_waitcnt vmcnt(0)" ::: "memory");
}

// ---------------------------------------------------------------------------
extern "C" void kernel_launch(void* const* d_in, const int* in_sizes, int n_in,
                              void* d_out, int out_size, void* d_ws, size_t ws_size,
                              hipStream_t stream) {
    const float* x  = (const float*)d_in[0];
    const float* h  = (const float*)d_in[1];
    const float* c  = (const float*)d_in[2];
    const float* W  = (const float*)d_in[3];
    const float* bW = (const float*)d_in[4];
    const float* U  = (const float*)d_in[5];
    const float* bU = (const float*)d_in[6];
    float* out = (float*)d_out;

    char* ws = (char*)d_ws;
    unsigned short* Xc = (unsigned short*)ws;                         // 16 MB
    unsigned short* Wc = (unsigned short*)(ws + ((size_t)16 << 20));  // 16 MB
    float* bsum = (float*)(ws + ((size_t)32 << 20));                  // 16 KB

    (void)hipFuncSetAttribute((const void*)gemm_8ph,
                              hipFuncAttributeMaxDynamicSharedMemorySize, 131072);

    hipLaunchKernelGGL(pack_bf16, dim3(2048), dim3(256), 0, stream,
                       x, h, W, U, bW, bU, Xc, Wc, bsum);
    hipLaunchKernelGGL(gemm_8ph, dim3(256), dim3(512), 131072, stream,
                       Xc, Wc, bsum, c, out);
}